// Round 3
// baseline (1516.542 us; speedup 1.0000x reference)
//
#include <hip/hip_runtime.h>

// PatchDivider R2: permutation-gather restructured as a 2-level binning sort
// so ALL fabric traffic is coalesced/L2-local instead of random 64B fetches.
//
// orders is a permutation of [0, 4194304) => bin populations are EXACT:
//   src-bin  b (src>>16): exactly 65536 entries
//   dst-bin  d (dst>>12): exactly 4096 entries (= 64 whole patches)
//
// K0: init bin cursors (re-run every launch; ws is NOT re-poisoned).
// K1: stream orders; partition (dst,src) into 64 src-bins (LDS hist +
//     one global atomicAdd per bin per block -> chunky contiguous runs).
// K2: per src-bin, XCD-pinned (bid&7): read pairs coalesced, gather pts
//     inside the bin's 786KB window (hot in that XCD's L2 -> each pts
//     line fetched once, all ~5.3 contained points consumed), append
//     {xyz, dst} to fine dst-bins via atomic cursors.
// K3: per dst-bin: coalesced read of exactly 4096 entries, scatter into
//     LDS by dst&4095, per-wave 64-lane butterfly mean, coalesced
//     centered writes + centers. Output fully deterministic.

#define PD_TOTAL  (32 * 131072)            // 4,194,304 points
#define PD_PATCH  64
#define PD_NPATCH (PD_TOTAL / PD_PATCH)    // 65,536
#define NSB   64
#define SRCB  (PD_TOTAL / NSB)             // 65,536 = 2^16
#define NDB   1024
#define DSTB  (PD_TOTAL / NDB)             // 4,096  = 2^12

// ws layout (bytes)
#define WS_PAIRS1_OFF 0
#define WS_PAIRS1_SZ  ((size_t)PD_TOTAL * 8)               // uint2
#define WS_PAIRS2_OFF (WS_PAIRS1_OFF + WS_PAIRS1_SZ)       // 16B aligned
#define WS_PAIRS2_SZ  ((size_t)PD_TOTAL * 16)              // float4
#define WS_CUR1_OFF   (WS_PAIRS2_OFF + WS_PAIRS2_SZ)
#define WS_CUR2_OFF   (WS_CUR1_OFF + NSB * 4)
#define WS_NEEDED     (WS_CUR2_OFF + NDB * 4)

struct pt3 { float x, y, z; };

// ---------------- K0: cursor init ----------------
__global__ void pd_init(int* gcur1, int* gcur2) {
    int t = threadIdx.x;
    if (t < NSB) gcur1[t] = t * SRCB;
    if (t < NDB) gcur2[t] = t * DSTB;
}

// ---------------- K1: src-binning of (dst,src) ----------------
// 2048 blocks x 256 thr, 2048 entries/block (8/thread)
__global__ __launch_bounds__(256) void pd_bin_src(
    const int* __restrict__ orders, uint2* __restrict__ pairs1,
    int* __restrict__ gcur1)
{
    __shared__ int hist[NSB];
    __shared__ int basec[NSB];
    const int tid = threadIdx.x;
    const int base = blockIdx.x * 2048;
    if (tid < NSB) hist[tid] = 0;
    __syncthreads();

    unsigned dst[8], src[8];
    #pragma unroll
    for (int k = 0; k < 8; ++k) {
        dst[k] = base + tid + k * 256;
        src[k] = (unsigned)orders[dst[k]];
    }
    #pragma unroll
    for (int k = 0; k < 8; ++k)
        atomicAdd(&hist[src[k] >> 16], 1);
    __syncthreads();

    if (tid < NSB)
        basec[tid] = atomicAdd(&gcur1[tid], hist[tid]);
    __syncthreads();

    #pragma unroll
    for (int k = 0; k < 8; ++k) {
        const unsigned b = src[k] >> 16;
        const int slot = atomicAdd(&basec[b], 1);
        pairs1[slot] = make_uint2(dst[k], src[k]);
    }
}

// ---------------- K2: hot-window gather + dst-binning ----------------
// 4096 blocks x 256 thr, 1024 entries/block (4/thread)
// bid -> bin so that all 64 blocks of a bin share one XCD (bid&7 pin):
//   bin = (bid&7) + 8*(bid>>9); chunk = (bid>>3)&63
__global__ __launch_bounds__(256) void pd_gather(
    const float* __restrict__ pts, const uint2* __restrict__ pairs1,
    float4* __restrict__ pairs2, int* __restrict__ gcur2)
{
    const int bid = blockIdx.x;
    const int bin = (bid & 7) + 8 * (bid >> 9);
    const int chunk = (bid >> 3) & 63;
    const int start = bin * SRCB + chunk * 1024;
    const int tid = threadIdx.x;

    uint2 e[4];
    #pragma unroll
    for (int k = 0; k < 4; ++k)
        e[k] = pairs1[start + tid + k * 256];

    pt3 q[4];
    #pragma unroll
    for (int k = 0; k < 4; ++k)
        q[k] = *(const pt3*)(pts + (size_t)e[k].y * 3);

    #pragma unroll
    for (int k = 0; k < 4; ++k) {
        const unsigned d = e[k].x >> 12;
        const int slot = atomicAdd(&gcur2[d], 1);
        pairs2[slot] = make_float4(q[k].x, q[k].y, q[k].z,
                                   __uint_as_float(e[k].x));
    }
}

// ---------------- K3: per-dst-bin LDS assemble + mean + write ----------------
// 1024 blocks x 256 thr; bin g == dst range [g*4096, (g+1)*4096) == 64 patches
__global__ __launch_bounds__(256) void pd_finish(
    const float4* __restrict__ pairs2, float* __restrict__ out)
{
    __shared__ float lpt[DSTB * 3];        // 48 KB
    const int g = blockIdx.x;
    const int tid = threadIdx.x;

    #pragma unroll
    for (int k = 0; k < 16; ++k) {
        const float4 e = pairs2[(size_t)g * DSTB + tid + k * 256];
        const unsigned l = __float_as_uint(e.w) & (DSTB - 1);
        lpt[l * 3 + 0] = e.x;
        lpt[l * 3 + 1] = e.y;
        lpt[l * 3 + 2] = e.z;
    }
    __syncthreads();

    const int w = tid >> 6, lane = tid & 63;
    const float inv = 1.0f / (float)PD_PATCH;
    for (int p = w * 16; p < w * 16 + 16; ++p) {
        const int li = (p * 64 + lane) * 3;
        const float x = lpt[li + 0];
        const float y = lpt[li + 1];
        const float z = lpt[li + 2];
        float sx = x, sy = y, sz = z;
        #pragma unroll
        for (int off = 32; off >= 1; off >>= 1) {
            sx += __shfl_xor(sx, off, 64);
            sy += __shfl_xor(sy, off, 64);
            sz += __shfl_xor(sz, off, 64);
        }
        const float cx = sx * inv, cy = sy * inv, cz = sz * inv;
        float* po = out + ((size_t)g * DSTB + p * 64 + lane) * 3;
        pt3 r = { x - cx, y - cy, z - cz };
        *(pt3*)po = r;
        if (lane == 0) {
            float* co = out + (size_t)PD_TOTAL * 3 + ((size_t)g * 64 + p) * 3;
            pt3 c = { cx, cy, cz };
            *(pt3*)co = c;
        }
    }
}

// ---------------- fallback: R0 wave-per-patch gather ----------------
__global__ __launch_bounds__(256) void pd_simple(
    const float* __restrict__ pts, const int* __restrict__ orders,
    float* __restrict__ out)
{
    const int gtid = blockIdx.x * blockDim.x + threadIdx.x;
    const int wave = gtid >> 6;
    const int lane = threadIdx.x & 63;
    const long long point = (long long)wave * PD_PATCH + lane;
    const int idx = orders[point];
    const pt3 q = *(const pt3*)(pts + (size_t)idx * 3);
    float sx = q.x, sy = q.y, sz = q.z;
    #pragma unroll
    for (int off = 32; off >= 1; off >>= 1) {
        sx += __shfl_xor(sx, off, 64);
        sy += __shfl_xor(sy, off, 64);
        sz += __shfl_xor(sz, off, 64);
    }
    const float inv = 1.0f / (float)PD_PATCH;
    const float cx = sx * inv, cy = sy * inv, cz = sz * inv;
    float* po = out + point * 3;
    pt3 r = { q.x - cx, q.y - cy, q.z - cz };
    *(pt3*)po = r;
    if (lane == 0) {
        float* co = out + (size_t)PD_TOTAL * 3 + (size_t)wave * 3;
        pt3 c = { cx, cy, cz };
        *(pt3*)co = c;
    }
}

extern "C" void kernel_launch(void* const* d_in, const int* in_sizes, int n_in,
                              void* d_out, int out_size, void* d_ws, size_t ws_size,
                              hipStream_t stream) {
    const float* pts  = (const float*)d_in[0];
    const int* orders = (const int*)d_in[1];
    float* out        = (float*)d_out;

    if (ws_size < WS_NEEDED) {
        // not enough scratch: fall back to direct gather
        pd_simple<<<PD_TOTAL / 256, 256, 0, stream>>>(pts, orders, out);
        return;
    }

    char* ws = (char*)d_ws;
    uint2*  pairs1 = (uint2*) (ws + WS_PAIRS1_OFF);
    float4* pairs2 = (float4*)(ws + WS_PAIRS2_OFF);
    int*    gcur1  = (int*)   (ws + WS_CUR1_OFF);
    int*    gcur2  = (int*)   (ws + WS_CUR2_OFF);

    pd_init   <<<1, 1024, 0, stream>>>(gcur1, gcur2);
    pd_bin_src<<<PD_TOTAL / 2048, 256, 0, stream>>>(orders, pairs1, gcur1);
    pd_gather <<<PD_TOTAL / 1024, 256, 0, stream>>>(pts, pairs1, pairs2, gcur2);
    pd_finish <<<NDB, 256, 0, stream>>>(pairs2, out);
}

// Round 4
// 99.255 us; speedup vs baseline: 15.2792x; 15.2792x over previous
//
#include <hip/hip_runtime.h>

// PatchDivider R3: single-kernel windowed permutation.
//
// - 2048 blocks x 256 threads, ALL co-resident (0 LDS, <=64 VGPR target).
// - dst-sharded: XCD x (bid&7) owns dst [x*524288, (x+1)*524288);
//   block owns 2048 contiguous dst = 32 whole patches; thread owns 8
//   consecutive dst points, kept in registers end-to-end.
// - src swept in 32 windows of 131072 points (1.57 MB of pts — resident in
//   the XCD's 4 MB L2 during its sweep). Gathers become L2 HITS instead of
//   random L3/HBM line fetches (R0/R1's ~3.5 TB/s latency wall).
// - epilogue: patch mean = per-thread 8-point sum + shfl_xor(1,2,4) over the
//   8-thread group; subtract in-register; coalesced centered writes+centers.
// - no atomics, no workspace, no second pass. Deterministic.

#define PD_TOTAL  (32 * 131072)          // 4,194,304 points
#define PD_PATCH  64
#define PD_NPATCH (PD_TOTAL / PD_PATCH)  // 65,536
#define NXCD      8
#define PER_XCD   (PD_TOTAL / NXCD)      // 524,288
#define NBLK      2048
#define BPX       (NBLK / NXCD)          // 256 blocks per XCD
#define CHUNK     2048                   // dst entries per block
#define PPT       8                      // points per thread
#define NW        32
#define WSHIFT    17                     // PD_TOTAL/NW = 131072 = 2^17

__global__ __launch_bounds__(256, 8) void pd_window(
    const float* __restrict__ pts,
    const int* __restrict__ orders,
    float* __restrict__ out)
{
    const int bid = blockIdx.x;          // 0..2047
    const int xcd = bid & 7;
    const int blk = bid >> 3;            // 0..255
    const int t   = threadIdx.x;
    const int dst0 = xcd * PER_XCD + blk * CHUNK + t * PPT;

    // thread's 8 src indices: 32B contiguous, two dwordx4 loads
    int src[PPT];
    const int4 s0 = *(const int4*)(orders + dst0);
    const int4 s1 = *(const int4*)(orders + dst0 + 4);
    src[0] = s0.x; src[1] = s0.y; src[2] = s0.z; src[3] = s0.w;
    src[4] = s1.x; src[5] = s1.y; src[6] = s1.z; src[7] = s1.w;

    float qx[PPT], qy[PPT], qz[PPT];

    // windowed sweep: gather each point when its window is L2-hot
    for (int w = 0; w < NW; ++w) {
        #pragma unroll
        for (int j = 0; j < PPT; ++j) {
            if ((src[j] >> WSHIFT) == w) {
                const float* p = pts + (size_t)src[j] * 3;
                qx[j] = p[0];
                qy[j] = p[1];
                qz[j] = p[2];
            }
        }
    }

    // patch mean: 8 threads (t&~7 .. t|7) hold one 64-point patch
    float sx = 0.f, sy = 0.f, sz = 0.f;
    #pragma unroll
    for (int j = 0; j < PPT; ++j) { sx += qx[j]; sy += qy[j]; sz += qz[j]; }
    #pragma unroll
    for (int off = 1; off <= 4; off <<= 1) {
        sx += __shfl_xor(sx, off, 64);
        sy += __shfl_xor(sy, off, 64);
        sz += __shfl_xor(sz, off, 64);
    }
    const float inv = 1.0f / (float)PD_PATCH;
    const float cx = sx * inv, cy = sy * inv, cz = sz * inv;

    // subtract in-register, write 24 floats (96B contiguous) as float2s
    #pragma unroll
    for (int j = 0; j < PPT; ++j) { qx[j] -= cx; qy[j] -= cy; qz[j] -= cz; }

    float* po = out + (size_t)dst0 * 3;          // 96B-aligned
    float2* po2 = (float2*)po;
    #pragma unroll
    for (int j = 0; j < PPT; j += 2) {
        // two points = 6 floats = 3x float2
        po2[0] = make_float2(qx[j],     qy[j]);
        po2[1] = make_float2(qz[j],     qx[j + 1]);
        po2[2] = make_float2(qy[j + 1], qz[j + 1]);
        po2 += 3;
    }

    // one lane per 8-lane group writes the patch center
    if ((t & 7) == 0) {
        float* co = out + (size_t)PD_TOTAL * 3 + (size_t)(dst0 >> 6) * 3;
        co[0] = cx; co[1] = cy; co[2] = cz;
    }
}

extern "C" void kernel_launch(void* const* d_in, const int* in_sizes, int n_in,
                              void* d_out, int out_size, void* d_ws, size_t ws_size,
                              hipStream_t stream) {
    const float* pts  = (const float*)d_in[0];
    const int* orders = (const int*)d_in[1];
    float* out        = (float*)d_out;

    pd_window<<<NBLK, 256, 0, stream>>>(pts, orders, out);
}

// Round 5
// 95.477 us; speedup vs baseline: 15.8839x; 1.0396x over previous
//
#include <hip/hip_runtime.h>

// PatchDivider R4: dense src-sorted gather via per-block LDS binning.
//
// Block owns 4096 contiguous dst (= 64 patches). Pipeline per block:
//  1. load 4096 (dst,src) pairs (coalesced), LDS histogram of src>>16 (64 bins)
//  2. exclusive scan (wave 0), scatter pairs into LDS in src-sorted order
//  3. gather pts in sorted order with FULL dense lane masks (16 iters/thread)
//     -> all blocks sweep src ascending together; live src span ~3MB/XCD
//        stays L2-resident; each 64B pts line fetched ~once, ~5.3 pts consumed
//  4. results land in LDS at dst-local slot (deterministic: output position
//     and value independent of LDS-atomic race order)
//  5. wave-per-patch butterfly mean + coalesced centered writes + centers
//
// No global atomics, no workspace. LDS 72.5 KB -> 2 blocks/CU.

#define PD_TOTAL  (32 * 131072)          // 4,194,304
#define PD_PATCH  64
#define CHUNK     4096                   // dsts per block (= 64 patches)
#define NBLK      (PD_TOTAL / CHUNK)     // 1024
#define PPT       16                     // pairs per thread (4096/256)
#define NBIN      64
#define BSHIFT    16                     // src>>16 in [0,64)

struct pt3 { float x, y, z; };

__global__ __launch_bounds__(256, 2) void pd_sorted(
    const float* __restrict__ pts,
    const int* __restrict__ orders,
    float* __restrict__ out)
{
    __shared__ unsigned       ssrc[CHUNK];        // 16 KB  src, sorted by bin
    __shared__ unsigned short sdl [CHUNK];        //  8 KB  dst-local, sorted
    __shared__ float          res [CHUNK * 3];    // 48 KB  gathered pts @ dst-local
    __shared__ int hist[NBIN];                    // bin counts -> unused after scan
    __shared__ int bincur[NBIN];                  // scatter cursors

    const int t    = threadIdx.x;
    const int base = blockIdx.x * CHUNK;

    if (t < NBIN) hist[t] = 0;
    __syncthreads();

    // 1. load pairs (coalesced stride-256) + histogram
    unsigned src[PPT];
    #pragma unroll
    for (int j = 0; j < PPT; ++j) {
        src[j] = (unsigned)orders[base + t + j * 256];
        atomicAdd(&hist[src[j] >> BSHIFT], 1);
    }
    __syncthreads();

    // 2. exclusive scan over 64 bins (wave 0)
    if (t < NBIN) {
        const int v = hist[t];
        int incl = v;
        #pragma unroll
        for (int off = 1; off < NBIN; off <<= 1) {
            const int n = __shfl_up(incl, off, 64);
            if (t >= off) incl += n;
        }
        bincur[t] = incl - v;        // exclusive prefix
    }
    __syncthreads();

    // scatter pairs into src-sorted LDS order
    #pragma unroll
    for (int j = 0; j < PPT; ++j) {
        const int pos = atomicAdd(&bincur[src[j] >> BSHIFT], 1);
        ssrc[pos] = src[j];
        sdl [pos] = (unsigned short)(t + j * 256);
    }
    __syncthreads();

    // 3+4. dense gather in sorted order -> res[dst-local]
    #pragma unroll
    for (int j = 0; j < PPT; ++j) {
        const int i = j * 256 + t;
        const unsigned s  = ssrc[i];
        const unsigned dl = sdl[i];
        const pt3 q = *(const pt3*)(pts + (size_t)s * 3);
        res[dl * 3 + 0] = q.x;
        res[dl * 3 + 1] = q.y;
        res[dl * 3 + 2] = q.z;
    }
    __syncthreads();

    // 5. epilogue: 64 patches, 4 waves x 16 patches, butterfly mean
    const int w = t >> 6, lane = t & 63;
    const float inv = 1.0f / (float)PD_PATCH;
    for (int p = w; p < 64; p += 4) {
        const int li = (p * 64 + lane) * 3;
        const float x = res[li + 0];
        const float y = res[li + 1];
        const float z = res[li + 2];
        float sx = x, sy = y, sz = z;
        #pragma unroll
        for (int off = 32; off >= 1; off >>= 1) {
            sx += __shfl_xor(sx, off, 64);
            sy += __shfl_xor(sy, off, 64);
            sz += __shfl_xor(sz, off, 64);
        }
        const float cx = sx * inv, cy = sy * inv, cz = sz * inv;

        float* po = out + ((size_t)base + p * 64 + lane) * 3;
        pt3 r = { x - cx, y - cy, z - cz };
        *(pt3*)po = r;

        if (lane == 0) {
            float* co = out + (size_t)PD_TOTAL * 3
                            + ((size_t)blockIdx.x * 64 + p) * 3;
            pt3 c = { cx, cy, cz };
            *(pt3*)co = c;
        }
    }
}

extern "C" void kernel_launch(void* const* d_in, const int* in_sizes, int n_in,
                              void* d_out, int out_size, void* d_ws, size_t ws_size,
                              hipStream_t stream) {
    const float* pts  = (const float*)d_in[0];
    const int* orders = (const int*)d_in[1];
    float* out        = (float*)d_out;

    pd_sorted<<<NBLK, 256, 0, stream>>>(pts, orders, out);
}